// Round 10
// baseline (275.766 us; speedup 1.0000x reference)
//
#include <hip/hip_runtime.h>
#include <hip/hip_fp16.h>

#define CCH 64
#define NBLK 512        // phase-A partition blocks (512 -> all CUs busy)
#define BKT  256        // nodes per bucket

// ---------------- Phase A: partitioned counting sort of edges by dst ----------------
// R10: also accumulates per-node in-degree (global atomics) so dinv/tohalf can
// run in a dedicated well-occupied kernel instead of starved buildB.

__global__ void countA(const int* __restrict__ dst, int* __restrict__ cntmat,
                       int* __restrict__ deg, int E, int chunk, int B) {
    __shared__ int h[512];
    int t = threadIdx.x, blk = blockIdx.x;
    for (int i = t; i < B; i += 256) h[i] = 0;
    __syncthreads();
    int e0 = blk * chunk, e1 = min(e0 + chunk, E);
    for (int e = e0 + t; e < e1; e += 256) {
        int d = dst[e];
        atomicAdd(&h[d >> 8], 1);
        atomicAdd(&deg[d], 1);
    }
    __syncthreads();
    for (int i = t; i < B; i += 256) cntmat[i * NBLK + blk] = h[i];
}

// Level-1 scan (1024 elems / block); bsum gets per-block totals (NOT scanned --
// consumers inline-scan it).
__global__ void scan1(const int* __restrict__ cnt, int* __restrict__ part,
                      int* __restrict__ bsum, int N) {
    __shared__ int s[256];
    int t = threadIdx.x;
    int base = blockIdx.x * 1024 + t * 4;
    int v0 = (base + 0 < N) ? cnt[base + 0] : 0;
    int v1 = (base + 1 < N) ? cnt[base + 1] : 0;
    int v2 = (base + 2 < N) ? cnt[base + 2] : 0;
    int v3 = (base + 3 < N) ? cnt[base + 3] : 0;
    s[t] = v0 + v1 + v2 + v3;
    __syncthreads();
    for (int off = 1; off < 256; off <<= 1) {
        int xx = (t >= off) ? s[t - off] : 0;
        __syncthreads();
        s[t] += xx;
        __syncthreads();
    }
    int excl = (t == 0) ? 0 : s[t - 1];
    if (t == 255) bsum[blockIdx.x] = s[255];
    if (base + 0 < N) part[base + 0] = excl;
    if (base + 1 < N) part[base + 1] = excl + v0;
    if (base + 2 < N) part[base + 2] = excl + v0 + v1;
    if (base + 3 < N) part[base + 3] = excl + v0 + v1 + v2;
}

// inline exclusive scan of bsum[0..NB2) into sbs[] (NB2 <= 256).
__device__ __forceinline__ void scan_bsum(const int* __restrict__ bsum, int NB2,
                                          int* sbs, int t) {
    int v = (t < NB2) ? bsum[t] : 0;
    sbs[t] = v;
    __syncthreads();
    for (int o = 1; o < 256; o <<= 1) {
        int xx = (t >= o) ? sbs[t - o] : 0;
        __syncthreads();
        sbs[t] += xx;
        __syncthreads();
    }
    int e = sbs[t] - v;
    __syncthreads();
    sbs[t] = e;
    __syncthreads();
}

// partition: write (src<<8 | dst&255) into per-(block,bucket) exclusive ranges.
__global__ void partA(const int* __restrict__ src, const int* __restrict__ dst,
                      const int* __restrict__ part, const int* __restrict__ bsum,
                      unsigned* __restrict__ brec, int E, int chunk, int B, int NB2) {
    __shared__ int cur[512];
    __shared__ int sbs[256];
    int t = threadIdx.x, blk = blockIdx.x;
    scan_bsum(bsum, NB2, sbs, t);
    for (int i = t; i < B; i += 256) {
        int idx = i * NBLK + blk;
        cur[i] = part[idx] + sbs[idx >> 10];
    }
    __syncthreads();
    int e0 = blk * chunk, e1 = min(e0 + chunk, E);
    for (int e = e0 + t; e < e1; e += 256) {
        int s = src[e], d = dst[e];
        int pos = atomicAdd(&cur[d >> 8], 1);
        brec[pos] = ((unsigned)s << 8) | (unsigned)(d & 255);
    }
}

// ---------------- u0 = fp16(dinv*x) + dinv/dinv2 (dedicated, well-occupied) ----------
__global__ void __launch_bounds__(256, 8)
tohalfK(const int* __restrict__ deg, const float* __restrict__ x,
        float* __restrict__ dinv, float* __restrict__ dinv2,
        __half* __restrict__ xh, int N) {
    int t = threadIdx.x;
    int node = blockIdx.x * 32 + (t >> 3);
    if (node >= N) return;
    int q = t & 7;
    float dp1 = (float)deg[node] + 1.0f;      // degree incl. self-loop
    float di = rsqrtf(dp1);
    if (q == 0) { dinv[node] = di; dinv2[node] = 1.0f / dp1; }
    size_t base = (size_t)node * 64 + (size_t)q * 8;
    float4 a = *(const float4*)&x[base];
    float4 c = *(const float4*)&x[base + 4];
    float4 o;
    __half2* op = (__half2*)&o;
    op[0] = __float22half2_rn(make_float2(di * a.x, di * a.y));
    op[1] = __float22half2_rn(make_float2(di * a.z, di * a.w));
    op[2] = __float22half2_rn(make_float2(di * c.x, di * c.y));
    op[3] = __float22half2_rn(make_float2(di * c.z, di * c.w));
    *(float4*)&xh[base] = o;
}

// ---------------- Phase B: per-bucket CSR finalize (slim) ----------------
__global__ void buildB(const unsigned* __restrict__ brec, const int* __restrict__ part,
                       const int* __restrict__ bsum, int* __restrict__ row_ptr,
                       int* __restrict__ adj, int N, int B, int E, int NB2) {
    __shared__ int hist[256];
    __shared__ int scanbuf[256];
    __shared__ int cursor[256];
    __shared__ int sbs[256];
    int t = threadIdx.x, k = blockIdx.x;
    scan_bsum(bsum, NB2, sbs, t);
    int i0 = k * NBLK;
    int base = part[i0] + sbs[i0 >> 10];
    int nextb;
    if (k + 1 < B) {
        int i1 = (k + 1) * NBLK;
        nextb = part[i1] + sbs[i1 >> 10];
    } else {
        nextb = E;
    }
    hist[t] = 0;
    __syncthreads();
    for (int i = base + t; i < nextb; i += 256) atomicAdd(&hist[brec[i] & 255u], 1);
    __syncthreads();
    int v = hist[t];
    scanbuf[t] = v;
    __syncthreads();
    for (int o = 1; o < 256; o <<= 1) {
        int xx = (t >= o) ? scanbuf[t - o] : 0;
        __syncthreads();
        scanbuf[t] += xx;
        __syncthreads();
    }
    int excl = scanbuf[t] - v;
    int node = k * 256 + t;
    if (node < N) {
        int p = base + excl;
        row_ptr[node] = p;
        cursor[t] = p;
    }
    if (k == 0 && t == 0) row_ptr[N] = E;
    __syncthreads();
    for (int i = base + t; i < nextb; i += 256) {
        unsigned r = brec[i];
        int pos = atomicAdd(&cursor[r & 255u], 1);
        adj[pos] = (int)(r >> 8);
    }
}

// ---------------- propagation: u_out[i] = scale[i] * (u[i] + sum_j u[j]) ----------------
// Group-per-node, 8 nodes/wave, CONTIGUOUS node blocks, float4 (128B) gathers
// only. Measured-best R5/R7 body, byte-identical. (R2/R8: node order is
// load-bearing -- no permutation. R6: pipeline depth is VGPR-bounded.
// R9: transposes pay on one side; strided global reads lose to hidden LDS
// conflicts.)

__device__ __forceinline__ void acc16w(float4 hv, float w, float* acc) {
    __half2* hp = (__half2*)&hv;
    #pragma unroll
    for (int i2 = 0; i2 < 4; ++i2) {
        float2 f = __half22float2(hp[i2]);
        acc[2 * i2]     = fmaf(w, f.x, acc[2 * i2]);
        acc[2 * i2 + 1] = fmaf(w, f.y, acc[2 * i2 + 1]);
    }
}

__device__ __forceinline__ void prop_body(const __half* __restrict__ hin,
                                          const int* __restrict__ row_ptr,
                                          const int* __restrict__ adj,
                                          int nodeC, int cnt, int g8, int q,
                                          int E, float* acc) {
    int rp0 = row_ptr[nodeC];

    int R = cnt;
    R = max(R, __shfl_xor(R, 8, 64));
    R = max(R, __shfl_xor(R, 16, 64));
    R = max(R, __shfl_xor(R, 32, 64));

    const float4* hin16 = (const float4*)hin;
    float4 selfv = hin16[(size_t)nodeC * 8 + q];

    int eCur = adj[rp0 + q];          // edges 0..7 of this group's node
    int eNxt = adj[rp0 + 8 + q];      // edges 8..15 (pad-safe)
    int j0 = __shfl(eCur, g8 + 0, 64); j0 = (0 < cnt) ? j0 : 0;
    int j1 = __shfl(eCur, g8 + 1, 64); j1 = (1 < cnt) ? j1 : 0;
    int j2 = __shfl(eCur, g8 + 2, 64); j2 = (2 < cnt) ? j2 : 0;
    int j3 = __shfl(eCur, g8 + 3, 64); j3 = (3 < cnt) ? j3 : 0;
    float4 gA0 = hin16[(size_t)j0 * 8 + q];
    float4 gA1 = hin16[(size_t)j1 * 8 + q];
    float4 gA2 = hin16[(size_t)j2 * 8 + q];
    float4 gA3 = hin16[(size_t)j3 * 8 + q];
    float4 gB0, gB1, gB2, gB3;

    acc16w(selfv, 1.f, acc);

    for (int r = 0; r < R; r += 8) {
        int t;
        t = r + 4; j0 = __shfl(eCur, g8 + (t & 7), 64); j0 = (t < cnt) ? j0 : 0;
        t = r + 5; j1 = __shfl(eCur, g8 + (t & 7), 64); j1 = (t < cnt) ? j1 : 0;
        t = r + 6; j2 = __shfl(eCur, g8 + (t & 7), 64); j2 = (t < cnt) ? j2 : 0;
        t = r + 7; j3 = __shfl(eCur, g8 + (t & 7), 64); j3 = (t < cnt) ? j3 : 0;
        gB0 = hin16[(size_t)j0 * 8 + q];
        gB1 = hin16[(size_t)j1 * 8 + q];
        gB2 = hin16[(size_t)j2 * 8 + q];
        gB3 = hin16[(size_t)j3 * 8 + q];
        float w;
        w = (r + 0 < cnt) ? 1.f : 0.f; acc16w(gA0, w, acc);
        w = (r + 1 < cnt) ? 1.f : 0.f; acc16w(gA1, w, acc);
        w = (r + 2 < cnt) ? 1.f : 0.f; acc16w(gA2, w, acc);
        w = (r + 3 < cnt) ? 1.f : 0.f; acc16w(gA3, w, acc);
        t = r + 8;  j0 = __shfl(eNxt, g8 + (t & 7), 64); j0 = (t < cnt) ? j0 : 0;
        t = r + 9;  j1 = __shfl(eNxt, g8 + (t & 7), 64); j1 = (t < cnt) ? j1 : 0;
        t = r + 10; j2 = __shfl(eNxt, g8 + (t & 7), 64); j2 = (t < cnt) ? j2 : 0;
        t = r + 11; j3 = __shfl(eNxt, g8 + (t & 7), 64); j3 = (t < cnt) ? j3 : 0;
        gA0 = hin16[(size_t)j0 * 8 + q];
        gA1 = hin16[(size_t)j1 * 8 + q];
        gA2 = hin16[(size_t)j2 * 8 + q];
        gA3 = hin16[(size_t)j3 * 8 + q];
        w = (r + 4 < cnt) ? 1.f : 0.f; acc16w(gB0, w, acc);
        w = (r + 5 < cnt) ? 1.f : 0.f; acc16w(gB1, w, acc);
        w = (r + 6 < cnt) ? 1.f : 0.f; acc16w(gB2, w, acc);
        w = (r + 7 < cnt) ? 1.f : 0.f; acc16w(gB3, w, acc);
        eCur = eNxt;
        int ao = rp0 + r + 16;
        ao = (ao > E + 96) ? (E + 96) : ao;   // stay inside the +128 pad
        eNxt = adj[ao + q];
    }
}

__global__ void __launch_bounds__(256, 8)
prop_kernel(const __half* __restrict__ hin, __half* __restrict__ hout,
            const int* __restrict__ row_ptr, const int* __restrict__ adj,
            const float* __restrict__ scale, int N, int E) {
    int wid  = (blockIdx.x * blockDim.x + threadIdx.x) >> 6;
    int lane = threadIdx.x & 63;
    int g    = lane >> 3;
    int q    = lane & 7;
    int nb   = wid << 3;
    if (nb >= N) return;
    int  node  = nb + g;
    bool valid = node < N;
    int  nodeC = valid ? node : (N - 1);
    int cnt = valid ? (row_ptr[nodeC + 1] - row_ptr[nodeC]) : 0;

    float acc[8] = {0.f, 0.f, 0.f, 0.f, 0.f, 0.f, 0.f, 0.f};
    prop_body(hin, row_ptr, adj, nodeC, cnt, g << 3, q, E, acc);

    if (valid) {
        float sc = scale[nodeC];
        float4 o;
        __half2* op = (__half2*)&o;
        op[0] = __float22half2_rn(make_float2(sc * acc[0], sc * acc[1]));
        op[1] = __float22half2_rn(make_float2(sc * acc[2], sc * acc[3]));
        op[2] = __float22half2_rn(make_float2(sc * acc[4], sc * acc[5]));
        op[3] = __float22half2_rn(make_float2(sc * acc[6], sc * acc[7]));
        ((float4*)hout)[(size_t)node * 8 + q] = o;   // coalesced 1KB wave store
    }
}

// ---------------- fused hop 4 + final: out = 2x + (dinv*acc) @ W^T + b - x_pre ----
// R7-exact (measured 44.4us): coalesced W float4 read + scalar LDS transpose
// writes (8-way conflicts accepted -- hidden; R9 proved the strided-read
// alternative is 10us worse), early-issue x/xp, hoisted-Wt GEMM.
__global__ void __launch_bounds__(256, 6)
prop_final_kernel(const __half* __restrict__ hin, const float* __restrict__ x,
                  const float* __restrict__ xp, const float* __restrict__ W,
                  const float* __restrict__ b, float* __restrict__ out,
                  const int* __restrict__ row_ptr, const int* __restrict__ adj,
                  const float* __restrict__ dinv, int N, int E) {
    __shared__ __align__(16) float Wt[64 * 68];   // Wt[k][c] = W[c][k]
    __shared__ __align__(16) float ht[32 * 68];   // h rows for this block
    int t = threadIdx.x;
    int nodeBase = blockIdx.x * 32;

    // stage W^T (coalesced float4 global read; scalar LDS writes)
    for (int i = t; i < 1024; i += 256) {
        int c  = i >> 4;
        int k4 = i & 15;
        float4 w4 = ((const float4*)W)[i];
        Wt[(k4 * 4 + 0) * 68 + c] = w4.x;
        Wt[(k4 * 4 + 1) * 68 + c] = w4.y;
        Wt[(k4 * 4 + 2) * 68 + c] = w4.z;
        Wt[(k4 * 4 + 3) * 68 + c] = w4.w;
    }

    // ---- hop 4 (prop body) ----
    int wv   = t >> 6;
    int lane = t & 63;
    int g    = lane >> 3;
    int q    = lane & 7;
    int nl   = wv * 8 + g;                  // node_local 0..31
    int node = nodeBase + nl;
    bool valid = node < N;
    int  nodeC = valid ? node : (N - 1);
    int cnt = valid ? (row_ptr[nodeC + 1] - row_ptr[nodeC]) : 0;

    float acc[8] = {0.f, 0.f, 0.f, 0.f, 0.f, 0.f, 0.f, 0.f};
    prop_body(hin, row_ptr, adj, nodeC, cnt, g << 3, q, E, acc);

    float sc = valid ? dinv[nodeC] : 0.f;   // invalid rows -> zeros in ht
    {
        float* hrow = &ht[nl * 68 + q * 8];
        float4 h0, h1;
        h0.x = sc * acc[0]; h0.y = sc * acc[1]; h0.z = sc * acc[2]; h0.w = sc * acc[3];
        h1.x = sc * acc[4]; h1.y = sc * acc[5]; h1.z = sc * acc[6]; h1.w = sc * acc[7];
        *(float4*)&hrow[0] = h0;
        *(float4*)&hrow[4] = h1;
    }

    // early-issue epilogue operands: latency hides under barrier + GEMM
    int r0 = t >> 4;                        // 0..15
    int c0 = (t & 15) * 4;
    int n0 = nodeBase + r0;
    int n1 = n0 + 16;
    int n0c = (n0 < N) ? n0 : (N - 1);
    int n1c = (n1 < N) ? n1 : (N - 1);
    float4 xv0 = *(const float4*)&x[n0c * 64 + c0];
    float4 pv0 = *(const float4*)&xp[n0c * 64 + c0];
    float4 xv1 = *(const float4*)&x[n1c * 64 + c0];
    float4 pv1 = *(const float4*)&xp[n1c * 64 + c0];
    float4 bv  = *(const float4*)&b[c0];

    __syncthreads();   // Wt staged + all waves' ht rows written

    // ---- final GEMM: Wt rows loaded once per k4, used for both node rows ----
    float4 av0 = make_float4(0.f, 0.f, 0.f, 0.f);
    float4 av1 = make_float4(0.f, 0.f, 0.f, 0.f);
    #pragma unroll 4
    for (int k4 = 0; k4 < 16; ++k4) {
        float4 w0 = *(const float4*)&Wt[(k4 * 4 + 0) * 68 + c0];
        float4 w1 = *(const float4*)&Wt[(k4 * 4 + 1) * 68 + c0];
        float4 w2 = *(const float4*)&Wt[(k4 * 4 + 2) * 68 + c0];
        float4 w3 = *(const float4*)&Wt[(k4 * 4 + 3) * 68 + c0];
        float4 ha = *(const float4*)&ht[r0 * 68 + k4 * 4];
        float4 hb = *(const float4*)&ht[(r0 + 16) * 68 + k4 * 4];
        av0.x = fmaf(ha.x, w0.x, av0.x); av0.y = fmaf(ha.x, w0.y, av0.y);
        av0.z = fmaf(ha.x, w0.z, av0.z); av0.w = fmaf(ha.x, w0.w, av0.w);
        av0.x = fmaf(ha.y, w1.x, av0.x); av0.y = fmaf(ha.y, w1.y, av0.y);
        av0.z = fmaf(ha.y, w1.z, av0.z); av0.w = fmaf(ha.y, w1.w, av0.w);
        av0.x = fmaf(ha.z, w2.x, av0.x); av0.y = fmaf(ha.z, w2.y, av0.y);
        av0.z = fmaf(ha.z, w2.z, av0.z); av0.w = fmaf(ha.z, w2.w, av0.w);
        av0.x = fmaf(ha.w, w3.x, av0.x); av0.y = fmaf(ha.w, w3.y, av0.y);
        av0.z = fmaf(ha.w, w3.z, av0.z); av0.w = fmaf(ha.w, w3.w, av0.w);
        av1.x = fmaf(hb.x, w0.x, av1.x); av1.y = fmaf(hb.x, w0.y, av1.y);
        av1.z = fmaf(hb.x, w0.z, av1.z); av1.w = fmaf(hb.x, w0.w, av1.w);
        av1.x = fmaf(hb.y, w1.x, av1.x); av1.y = fmaf(hb.y, w1.y, av1.y);
        av1.z = fmaf(hb.y, w1.z, av1.z); av1.w = fmaf(hb.y, w1.w, av1.w);
        av1.x = fmaf(hb.z, w2.x, av1.x); av1.y = fmaf(hb.z, w2.y, av1.y);
        av1.z = fmaf(hb.z, w2.z, av1.z); av1.w = fmaf(hb.z, w2.w, av1.w);
        av1.x = fmaf(hb.w, w3.x, av1.x); av1.y = fmaf(hb.w, w3.y, av1.y);
        av1.z = fmaf(hb.w, w3.z, av1.z); av1.w = fmaf(hb.w, w3.w, av1.w);
    }

    if (n0 < N) {
        int base = n0 * 64 + c0;
        float4 o;
        o.x = fmaf(2.f, xv0.x, av0.x + bv.x) - pv0.x;
        o.y = fmaf(2.f, xv0.y, av0.y + bv.y) - pv0.y;
        o.z = fmaf(2.f, xv0.z, av0.z + bv.z) - pv0.z;
        o.w = fmaf(2.f, xv0.w, av0.w + bv.w) - pv0.w;
        *(float4*)&out[base] = o;
    }
    if (n1 < N) {
        int base = n1 * 64 + c0;
        float4 o;
        o.x = fmaf(2.f, xv1.x, av1.x + bv.x) - pv1.x;
        o.y = fmaf(2.f, xv1.y, av1.y + bv.y) - pv1.y;
        o.z = fmaf(2.f, xv1.z, av1.z + bv.z) - pv1.z;
        o.w = fmaf(2.f, xv1.w, av1.w + bv.w) - pv1.w;
        *(float4*)&out[base] = o;
    }
}

extern "C" void kernel_launch(void* const* d_in, const int* in_sizes, int n_in,
                              void* d_out, int out_size, void* d_ws, size_t ws_size,
                              hipStream_t stream) {
    const float* x    = (const float*)d_in[0];
    const float* xpre = (const float*)d_in[1];
    const int*   ei   = (const int*)d_in[2];
    const float* W    = (const float*)d_in[3];
    const float* b    = (const float*)d_in[4];
    float* out = (float*)d_out;

    const int N = in_sizes[0] / CCH;
    const int E = in_sizes[2] / 2;
    const int* src = ei;
    const int* dst = ei + E;

    const int B     = (N + BKT - 1) / BKT;       // buckets (391)
    const int M     = B * NBLK;                  // count-matrix size
    const int chunk = (E + NBLK - 1) / NBLK;
    const int NB2   = (M + 1023) / 1024;         // scan1 blocks (196 <= 256)

    // workspace partition (256B aligned)
    char* p = (char*)d_ws;
    auto alloc = [&](size_t bytes) -> char* {
        char* r = p;
        p += (bytes + 255) & ~(size_t)255;
        return r;
    };
    int*      cntmat  = (int*)alloc((size_t)M * 4);
    int*      part    = (int*)alloc((size_t)M * 4);
    int*      bsum    = (int*)alloc((size_t)NB2 * 4);
    unsigned* brec    = (unsigned*)alloc((size_t)E * 4);
    int*      adj     = (int*)alloc(((size_t)E + 128) * 4);  // +128 pad
    int*      row_ptr = (int*)alloc(((size_t)N + 1) * 4);
    int*      deg     = (int*)alloc((size_t)N * 4);
    float*    dinv    = (float*)alloc((size_t)N * 4);
    float*    dinv2   = (float*)alloc((size_t)N * 4);
    __half*   xh      = (__half*)alloc((size_t)N * CCH * 2);
    __half*   g0      = (__half*)alloc((size_t)N * CCH * 2);
    __half*   g1      = (__half*)alloc((size_t)N * CCH * 2);

    hipMemsetAsync(deg, 0, (size_t)N * 4, stream);
    countA<<<NBLK, 256, 0, stream>>>(dst, cntmat, deg, E, chunk, B);
    scan1 <<<NB2, 256, 0, stream>>>(cntmat, part, bsum, M);
    partA <<<NBLK, 256, 0, stream>>>(src, dst, part, bsum, brec, E, chunk, B, NB2);
    tohalfK<<<(N + 31) / 32, 256, 0, stream>>>(deg, x, dinv, dinv2, xh, N);
    buildB<<<B, 256, 0, stream>>>(brec, part, bsum, row_ptr, adj, N, B, E, NB2);

    const int nwave = (N + 7) / 8;               // 8 nodes per wave
    const int pgrid = (nwave + 3) / 4;           // 4 waves per 256-thread block
    prop_kernel<<<pgrid, 256, 0, stream>>>(xh, g0, row_ptr, adj, dinv2, N, E); // hop 1
    prop_kernel<<<pgrid, 256, 0, stream>>>(g0, g1, row_ptr, adj, dinv2, N, E); // hop 2
    prop_kernel<<<pgrid, 256, 0, stream>>>(g1, g0, row_ptr, adj, dinv2, N, E); // hop 3
    // hop 4 + final fused (reads g0, writes out directly; g1 scratch only)
    prop_final_kernel<<<(N + 31) / 32, 256, 0, stream>>>(g0, x, xpre, W, b, out,
                                                         row_ptr, adj, dinv, N, E);
    (void)g1;
}

// Round 11
// 243.585 us; speedup vs baseline: 1.1321x; 1.1321x over previous
//
#include <hip/hip_runtime.h>
#include <hip/hip_fp16.h>

#define CCH 64
#define NBLK 128        // phase-A partition blocks
#define BKT  256        // nodes per bucket

// ---------------- Phase A: partitioned counting sort of edges by dst ----------------

__global__ void countA(const int* __restrict__ dst, int* __restrict__ cntmat,
                       int E, int chunk, int B) {
    __shared__ int h[512];
    int t = threadIdx.x, blk = blockIdx.x;
    for (int i = t; i < B; i += 256) h[i] = 0;
    __syncthreads();
    int e0 = blk * chunk, e1 = min(e0 + chunk, E);
    for (int e = e0 + t; e < e1; e += 256) atomicAdd(&h[dst[e] >> 8], 1);
    __syncthreads();
    for (int i = t; i < B; i += 256) cntmat[i * NBLK + blk] = h[i];
}

// Level-1 scan (1024 elems / block); bsum gets per-block totals (NOT scanned --
// consumers inline-scan it).
__global__ void scan1(const int* __restrict__ cnt, int* __restrict__ part,
                      int* __restrict__ bsum, int N) {
    __shared__ int s[256];
    int t = threadIdx.x;
    int base = blockIdx.x * 1024 + t * 4;
    int v0 = (base + 0 < N) ? cnt[base + 0] : 0;
    int v1 = (base + 1 < N) ? cnt[base + 1] : 0;
    int v2 = (base + 2 < N) ? cnt[base + 2] : 0;
    int v3 = (base + 3 < N) ? cnt[base + 3] : 0;
    s[t] = v0 + v1 + v2 + v3;
    __syncthreads();
    for (int off = 1; off < 256; off <<= 1) {
        int xx = (t >= off) ? s[t - off] : 0;
        __syncthreads();
        s[t] += xx;
        __syncthreads();
    }
    int excl = (t == 0) ? 0 : s[t - 1];
    if (t == 255) bsum[blockIdx.x] = s[255];
    if (base + 0 < N) part[base + 0] = excl;
    if (base + 1 < N) part[base + 1] = excl + v0;
    if (base + 2 < N) part[base + 2] = excl + v0 + v1;
    if (base + 3 < N) part[base + 3] = excl + v0 + v1 + v2;
}

// inline exclusive scan of bsum[0..NB2) into sbs[] (NB2 <= 256).
__device__ __forceinline__ void scan_bsum(const int* __restrict__ bsum, int NB2,
                                          int* sbs, int t) {
    int v = (t < NB2) ? bsum[t] : 0;
    sbs[t] = v;
    __syncthreads();
    for (int o = 1; o < 256; o <<= 1) {
        int xx = (t >= o) ? sbs[t - o] : 0;
        __syncthreads();
        sbs[t] += xx;
        __syncthreads();
    }
    int e = sbs[t] - v;
    __syncthreads();
    sbs[t] = e;
    __syncthreads();
}

// partition: write (src<<8 | dst&255) into per-(block,bucket) exclusive ranges.
__global__ void partA(const int* __restrict__ src, const int* __restrict__ dst,
                      const int* __restrict__ part, const int* __restrict__ bsum,
                      unsigned* __restrict__ brec, int E, int chunk, int B, int NB2) {
    __shared__ int cur[512];
    __shared__ int sbs[256];
    int t = threadIdx.x, blk = blockIdx.x;
    scan_bsum(bsum, NB2, sbs, t);
    for (int i = t; i < B; i += 256) {
        int idx = i * NBLK + blk;
        cur[i] = part[idx] + sbs[idx >> 10];
    }
    __syncthreads();
    int e0 = blk * chunk, e1 = min(e0 + chunk, E);
    for (int e = e0 + t; e < e1; e += 256) {
        int s = src[e], d = dst[e];
        int pos = atomicAdd(&cur[d >> 8], 1);
        brec[pos] = ((unsigned)s << 8) | (unsigned)(d & 255);
    }
}

// ---------------- Phase B: per-bucket CSR finalize + u0 = fp16(dinv*x) ----------------
// R7 form: degree/dinv/tohalf all derived from the bucket's LDS histogram
// (R10 lesson: never recompute globally what the histogram gives for free).
__global__ void buildB(const unsigned* __restrict__ brec, const int* __restrict__ part,
                       const int* __restrict__ bsum, int* __restrict__ row_ptr,
                       int* __restrict__ adj, float* __restrict__ dinv,
                       float* __restrict__ dinv2, const float* __restrict__ x,
                       __half* __restrict__ xh, int N, int B, int E, int NB2) {
    __shared__ int hist[256];
    __shared__ int scanbuf[256];
    __shared__ int cursor[256];
    __shared__ int sbs[256];
    __shared__ float sdinv[256];
    int t = threadIdx.x, k = blockIdx.x;
    scan_bsum(bsum, NB2, sbs, t);
    int i0 = k * NBLK;
    int base = part[i0] + sbs[i0 >> 10];
    int nextb;
    if (k + 1 < B) {
        int i1 = (k + 1) * NBLK;
        nextb = part[i1] + sbs[i1 >> 10];
    } else {
        nextb = E;
    }
    hist[t] = 0;
    __syncthreads();
    for (int i = base + t; i < nextb; i += 256) atomicAdd(&hist[brec[i] & 255u], 1);
    __syncthreads();
    int v = hist[t];
    scanbuf[t] = v;
    __syncthreads();
    for (int o = 1; o < 256; o <<= 1) {
        int xx = (t >= o) ? scanbuf[t - o] : 0;
        __syncthreads();
        scanbuf[t] += xx;
        __syncthreads();
    }
    int excl = scanbuf[t] - v;
    int node = k * 256 + t;
    float di = 0.f;
    if (node < N) {
        int p = base + excl;
        row_ptr[node] = p;
        cursor[t] = p;
        float dp1 = (float)v + 1.0f;          // degree incl. self-loop
        di = rsqrtf(dp1);
        dinv[node]  = di;
        dinv2[node] = 1.0f / dp1;
    }
    sdinv[t] = di;
    if (k == 0 && t == 0) row_ptr[N] = E;
    __syncthreads();
    for (int i = base + t; i < nextb; i += 256) {
        unsigned r = brec[i];
        int pos = atomicAdd(&cursor[r & 255u], 1);
        adj[pos] = (int)(r >> 8);
    }
    // fused tohalf for this bucket (coalesced; overlaps scatter latency)
    int nodeBase = k * 256;
    for (int i = t; i < 2048; i += 256) {
        int nl = i >> 3;
        int node2 = nodeBase + nl;
        if (node2 < N) {
            float d = sdinv[nl];
            size_t baseE = (size_t)node2 * 64 + (size_t)(i & 7) * 8;
            float4 a = *(const float4*)&x[baseE];
            float4 c = *(const float4*)&x[baseE + 4];
            float4 o;
            __half2* op = (__half2*)&o;
            op[0] = __float22half2_rn(make_float2(d * a.x, d * a.y));
            op[1] = __float22half2_rn(make_float2(d * a.z, d * a.w));
            op[2] = __float22half2_rn(make_float2(d * c.x, d * c.y));
            op[3] = __float22half2_rn(make_float2(d * c.z, d * c.w));
            *(float4*)&xh[baseE] = o;
        }
    }
}

// ---------------- propagation: u_out[i] = scale[i] * (u[i] + sum_j u[j]) ----------------
// Group-per-node, 8 nodes/wave, CONTIGUOUS node blocks, float4 (128B) gathers
// only. Measured-best R5/R7 body. (R2/R8: node order is load-bearing -- no
// permutation. R6: pipeline depth is VGPR-bounded. R9: transposes pay on one
// side. R10: no global atomics for histogram-derivable data.)
// R11 micro-fix: scale/dinv loads hoisted ABOVE prop_body (T14) so their
// ~500cy latency hides under the gather loop instead of serializing the tail.

__device__ __forceinline__ void acc16w(float4 hv, float w, float* acc) {
    __half2* hp = (__half2*)&hv;
    #pragma unroll
    for (int i2 = 0; i2 < 4; ++i2) {
        float2 f = __half22float2(hp[i2]);
        acc[2 * i2]     = fmaf(w, f.x, acc[2 * i2]);
        acc[2 * i2 + 1] = fmaf(w, f.y, acc[2 * i2 + 1]);
    }
}

__device__ __forceinline__ void prop_body(const __half* __restrict__ hin,
                                          const int* __restrict__ row_ptr,
                                          const int* __restrict__ adj,
                                          int nodeC, int cnt, int g8, int q,
                                          int E, float* acc) {
    int rp0 = row_ptr[nodeC];

    int R = cnt;
    R = max(R, __shfl_xor(R, 8, 64));
    R = max(R, __shfl_xor(R, 16, 64));
    R = max(R, __shfl_xor(R, 32, 64));

    const float4* hin16 = (const float4*)hin;
    float4 selfv = hin16[(size_t)nodeC * 8 + q];

    int eCur = adj[rp0 + q];          // edges 0..7 of this group's node
    int eNxt = adj[rp0 + 8 + q];      // edges 8..15 (pad-safe)
    int j0 = __shfl(eCur, g8 + 0, 64); j0 = (0 < cnt) ? j0 : 0;
    int j1 = __shfl(eCur, g8 + 1, 64); j1 = (1 < cnt) ? j1 : 0;
    int j2 = __shfl(eCur, g8 + 2, 64); j2 = (2 < cnt) ? j2 : 0;
    int j3 = __shfl(eCur, g8 + 3, 64); j3 = (3 < cnt) ? j3 : 0;
    float4 gA0 = hin16[(size_t)j0 * 8 + q];
    float4 gA1 = hin16[(size_t)j1 * 8 + q];
    float4 gA2 = hin16[(size_t)j2 * 8 + q];
    float4 gA3 = hin16[(size_t)j3 * 8 + q];
    float4 gB0, gB1, gB2, gB3;

    acc16w(selfv, 1.f, acc);

    for (int r = 0; r < R; r += 8) {
        int t;
        t = r + 4; j0 = __shfl(eCur, g8 + (t & 7), 64); j0 = (t < cnt) ? j0 : 0;
        t = r + 5; j1 = __shfl(eCur, g8 + (t & 7), 64); j1 = (t < cnt) ? j1 : 0;
        t = r + 6; j2 = __shfl(eCur, g8 + (t & 7), 64); j2 = (t < cnt) ? j2 : 0;
        t = r + 7; j3 = __shfl(eCur, g8 + (t & 7), 64); j3 = (t < cnt) ? j3 : 0;
        gB0 = hin16[(size_t)j0 * 8 + q];
        gB1 = hin16[(size_t)j1 * 8 + q];
        gB2 = hin16[(size_t)j2 * 8 + q];
        gB3 = hin16[(size_t)j3 * 8 + q];
        float w;
        w = (r + 0 < cnt) ? 1.f : 0.f; acc16w(gA0, w, acc);
        w = (r + 1 < cnt) ? 1.f : 0.f; acc16w(gA1, w, acc);
        w = (r + 2 < cnt) ? 1.f : 0.f; acc16w(gA2, w, acc);
        w = (r + 3 < cnt) ? 1.f : 0.f; acc16w(gA3, w, acc);
        t = r + 8;  j0 = __shfl(eNxt, g8 + (t & 7), 64); j0 = (t < cnt) ? j0 : 0;
        t = r + 9;  j1 = __shfl(eNxt, g8 + (t & 7), 64); j1 = (t < cnt) ? j1 : 0;
        t = r + 10; j2 = __shfl(eNxt, g8 + (t & 7), 64); j2 = (t < cnt) ? j2 : 0;
        t = r + 11; j3 = __shfl(eNxt, g8 + (t & 7), 64); j3 = (t < cnt) ? j3 : 0;
        gA0 = hin16[(size_t)j0 * 8 + q];
        gA1 = hin16[(size_t)j1 * 8 + q];
        gA2 = hin16[(size_t)j2 * 8 + q];
        gA3 = hin16[(size_t)j3 * 8 + q];
        w = (r + 4 < cnt) ? 1.f : 0.f; acc16w(gB0, w, acc);
        w = (r + 5 < cnt) ? 1.f : 0.f; acc16w(gB1, w, acc);
        w = (r + 6 < cnt) ? 1.f : 0.f; acc16w(gB2, w, acc);
        w = (r + 7 < cnt) ? 1.f : 0.f; acc16w(gB3, w, acc);
        eCur = eNxt;
        int ao = rp0 + r + 16;
        ao = (ao > E + 96) ? (E + 96) : ao;   // stay inside the +128 pad
        eNxt = adj[ao + q];
    }
}

__global__ void __launch_bounds__(256, 8)
prop_kernel(const __half* __restrict__ hin, __half* __restrict__ hout,
            const int* __restrict__ row_ptr, const int* __restrict__ adj,
            const float* __restrict__ scale, int N, int E) {
    int wid  = (blockIdx.x * blockDim.x + threadIdx.x) >> 6;
    int lane = threadIdx.x & 63;
    int g    = lane >> 3;
    int q    = lane & 7;
    int nb   = wid << 3;
    if (nb >= N) return;
    int  node  = nb + g;
    bool valid = node < N;
    int  nodeC = valid ? node : (N - 1);
    int cnt = valid ? (row_ptr[nodeC + 1] - row_ptr[nodeC]) : 0;
    float sc = scale[nodeC];                  // early-issue: hides under loop

    float acc[8] = {0.f, 0.f, 0.f, 0.f, 0.f, 0.f, 0.f, 0.f};
    prop_body(hin, row_ptr, adj, nodeC, cnt, g << 3, q, E, acc);

    if (valid) {
        float4 o;
        __half2* op = (__half2*)&o;
        op[0] = __float22half2_rn(make_float2(sc * acc[0], sc * acc[1]));
        op[1] = __float22half2_rn(make_float2(sc * acc[2], sc * acc[3]));
        op[2] = __float22half2_rn(make_float2(sc * acc[4], sc * acc[5]));
        op[3] = __float22half2_rn(make_float2(sc * acc[6], sc * acc[7]));
        ((float4*)hout)[(size_t)node * 8 + q] = o;   // coalesced 1KB wave store
    }
}

// ---------------- fused hop 4 + final: out = 2x + (dinv*acc) @ W^T + b - x_pre ----
// R7-exact (measured 44.4us): coalesced W float4 read + scalar LDS transpose
// writes (8-way conflicts accepted -- hidden; R9 proved the alternative is
// worse), early-issue x/xp, hoisted-Wt GEMM. R11: dinv also early-issued.
__global__ void __launch_bounds__(256, 6)
prop_final_kernel(const __half* __restrict__ hin, const float* __restrict__ x,
                  const float* __restrict__ xp, const float* __restrict__ W,
                  const float* __restrict__ b, float* __restrict__ out,
                  const int* __restrict__ row_ptr, const int* __restrict__ adj,
                  const float* __restrict__ dinv, int N, int E) {
    __shared__ __align__(16) float Wt[64 * 68];   // Wt[k][c] = W[c][k]
    __shared__ __align__(16) float ht[32 * 68];   // h rows for this block
    int t = threadIdx.x;
    int nodeBase = blockIdx.x * 32;

    // stage W^T (coalesced float4 global read; scalar LDS writes)
    for (int i = t; i < 1024; i += 256) {
        int c  = i >> 4;
        int k4 = i & 15;
        float4 w4 = ((const float4*)W)[i];
        Wt[(k4 * 4 + 0) * 68 + c] = w4.x;
        Wt[(k4 * 4 + 1) * 68 + c] = w4.y;
        Wt[(k4 * 4 + 2) * 68 + c] = w4.z;
        Wt[(k4 * 4 + 3) * 68 + c] = w4.w;
    }

    // ---- hop 4 (prop body) ----
    int wv   = t >> 6;
    int lane = t & 63;
    int g    = lane >> 3;
    int q    = lane & 7;
    int nl   = wv * 8 + g;                  // node_local 0..31
    int node = nodeBase + nl;
    bool valid = node < N;
    int  nodeC = valid ? node : (N - 1);
    int cnt = valid ? (row_ptr[nodeC + 1] - row_ptr[nodeC]) : 0;
    float scd = dinv[nodeC];                // early-issue: hides under loop

    float acc[8] = {0.f, 0.f, 0.f, 0.f, 0.f, 0.f, 0.f, 0.f};
    prop_body(hin, row_ptr, adj, nodeC, cnt, g << 3, q, E, acc);

    float sc = valid ? scd : 0.f;           // invalid rows -> zeros in ht
    {
        float* hrow = &ht[nl * 68 + q * 8];
        float4 h0, h1;
        h0.x = sc * acc[0]; h0.y = sc * acc[1]; h0.z = sc * acc[2]; h0.w = sc * acc[3];
        h1.x = sc * acc[4]; h1.y = sc * acc[5]; h1.z = sc * acc[6]; h1.w = sc * acc[7];
        *(float4*)&hrow[0] = h0;
        *(float4*)&hrow[4] = h1;
    }

    // early-issue epilogue operands: latency hides under barrier + GEMM
    int r0 = t >> 4;                        // 0..15
    int c0 = (t & 15) * 4;
    int n0 = nodeBase + r0;
    int n1 = n0 + 16;
    int n0c = (n0 < N) ? n0 : (N - 1);
    int n1c = (n1 < N) ? n1 : (N - 1);
    float4 xv0 = *(const float4*)&x[n0c * 64 + c0];
    float4 pv0 = *(const float4*)&xp[n0c * 64 + c0];
    float4 xv1 = *(const float4*)&x[n1c * 64 + c0];
    float4 pv1 = *(const float4*)&xp[n1c * 64 + c0];
    float4 bv  = *(const float4*)&b[c0];

    __syncthreads();   // Wt staged + all waves' ht rows written

    // ---- final GEMM: Wt rows loaded once per k4, used for both node rows ----
    float4 av0 = make_float4(0.f, 0.f, 0.f, 0.f);
    float4 av1 = make_float4(0.f, 0.f, 0.f, 0.f);
    #pragma unroll 4
    for (int k4 = 0; k4 < 16; ++k4) {
        float4 w0 = *(const float4*)&Wt[(k4 * 4 + 0) * 68 + c0];
        float4 w1 = *(const float4*)&Wt[(k4 * 4 + 1) * 68 + c0];
        float4 w2 = *(const float4*)&Wt[(k4 * 4 + 2) * 68 + c0];
        float4 w3 = *(const float4*)&Wt[(k4 * 4 + 3) * 68 + c0];
        float4 ha = *(const float4*)&ht[r0 * 68 + k4 * 4];
        float4 hb = *(const float4*)&ht[(r0 + 16) * 68 + k4 * 4];
        av0.x = fmaf(ha.x, w0.x, av0.x); av0.y = fmaf(ha.x, w0.y, av0.y);
        av0.z = fmaf(ha.x, w0.z, av0.z); av0.w = fmaf(ha.x, w0.w, av0.w);
        av0.x = fmaf(ha.y, w1.x, av0.x); av0.y = fmaf(ha.y, w1.y, av0.y);
        av0.z = fmaf(ha.y, w1.z, av0.z); av0.w = fmaf(ha.y, w1.w, av0.w);
        av0.x = fmaf(ha.z, w2.x, av0.x); av0.y = fmaf(ha.z, w2.y, av0.y);
        av0.z = fmaf(ha.z, w2.z, av0.z); av0.w = fmaf(ha.z, w2.w, av0.w);
        av0.x = fmaf(ha.w, w3.x, av0.x); av0.y = fmaf(ha.w, w3.y, av0.y);
        av0.z = fmaf(ha.w, w3.z, av0.z); av0.w = fmaf(ha.w, w3.w, av0.w);
        av1.x = fmaf(hb.x, w0.x, av1.x); av1.y = fmaf(hb.x, w0.y, av1.y);
        av1.z = fmaf(hb.x, w0.z, av1.z); av1.w = fmaf(hb.x, w0.w, av1.w);
        av1.x = fmaf(hb.y, w1.x, av1.x); av1.y = fmaf(hb.y, w1.y, av1.y);
        av1.z = fmaf(hb.y, w1.z, av1.z); av1.w = fmaf(hb.y, w1.w, av1.w);
        av1.x = fmaf(hb.z, w2.x, av1.x); av1.y = fmaf(hb.z, w2.y, av1.y);
        av1.z = fmaf(hb.z, w2.z, av1.z); av1.w = fmaf(hb.z, w2.w, av1.w);
        av1.x = fmaf(hb.w, w3.x, av1.x); av1.y = fmaf(hb.w, w3.y, av1.y);
        av1.z = fmaf(hb.w, w3.z, av1.z); av1.w = fmaf(hb.w, w3.w, av1.w);
    }

    if (n0 < N) {
        int base = n0 * 64 + c0;
        float4 o;
        o.x = fmaf(2.f, xv0.x, av0.x + bv.x) - pv0.x;
        o.y = fmaf(2.f, xv0.y, av0.y + bv.y) - pv0.y;
        o.z = fmaf(2.f, xv0.z, av0.z + bv.z) - pv0.z;
        o.w = fmaf(2.f, xv0.w, av0.w + bv.w) - pv0.w;
        *(float4*)&out[base] = o;
    }
    if (n1 < N) {
        int base = n1 * 64 + c0;
        float4 o;
        o.x = fmaf(2.f, xv1.x, av1.x + bv.x) - pv1.x;
        o.y = fmaf(2.f, xv1.y, av1.y + bv.y) - pv1.y;
        o.z = fmaf(2.f, xv1.z, av1.z + bv.z) - pv1.z;
        o.w = fmaf(2.f, xv1.w, av1.w + bv.w) - pv1.w;
        *(float4*)&out[base] = o;
    }
}

extern "C" void kernel_launch(void* const* d_in, const int* in_sizes, int n_in,
                              void* d_out, int out_size, void* d_ws, size_t ws_size,
                              hipStream_t stream) {
    const float* x    = (const float*)d_in[0];
    const float* xpre = (const float*)d_in[1];
    const int*   ei   = (const int*)d_in[2];
    const float* W    = (const float*)d_in[3];
    const float* b    = (const float*)d_in[4];
    float* out = (float*)d_out;

    const int N = in_sizes[0] / CCH;
    const int E = in_sizes[2] / 2;
    const int* src = ei;
    const int* dst = ei + E;

    const int B     = (N + BKT - 1) / BKT;       // buckets
    const int M     = B * NBLK;                  // count-matrix size
    const int chunk = (E + NBLK - 1) / NBLK;
    const int NB2   = (M + 1023) / 1024;         // scan1 blocks (<=256)

    // workspace partition (256B aligned)
    char* p = (char*)d_ws;
    auto alloc = [&](size_t bytes) -> char* {
        char* r = p;
        p += (bytes + 255) & ~(size_t)255;
        return r;
    };
    int*      cntmat  = (int*)alloc((size_t)M * 4);
    int*      part    = (int*)alloc((size_t)M * 4);
    int*      bsum    = (int*)alloc((size_t)NB2 * 4);
    unsigned* brec    = (unsigned*)alloc((size_t)E * 4);
    int*      adj     = (int*)alloc(((size_t)E + 128) * 4);  // +128 pad
    int*      row_ptr = (int*)alloc(((size_t)N + 1) * 4);
    float*    dinv    = (float*)alloc((size_t)N * 4);
    float*    dinv2   = (float*)alloc((size_t)N * 4);
    __half*   xh      = (__half*)alloc((size_t)N * CCH * 2);
    __half*   g0      = (__half*)alloc((size_t)N * CCH * 2);
    __half*   g1      = (__half*)alloc((size_t)N * CCH * 2);

    countA<<<NBLK, 256, 0, stream>>>(dst, cntmat, E, chunk, B);
    scan1 <<<NB2, 256, 0, stream>>>(cntmat, part, bsum, M);
    partA <<<NBLK, 256, 0, stream>>>(src, dst, part, bsum, brec, E, chunk, B, NB2);
    buildB<<<B, 256, 0, stream>>>(brec, part, bsum, row_ptr, adj, dinv, dinv2,
                                  x, xh, N, B, E, NB2);

    const int nwave = (N + 7) / 8;               // 8 nodes per wave
    const int pgrid = (nwave + 3) / 4;           // 4 waves per 256-thread block
    prop_kernel<<<pgrid, 256, 0, stream>>>(xh, g0, row_ptr, adj, dinv2, N, E); // hop 1
    prop_kernel<<<pgrid, 256, 0, stream>>>(g0, g1, row_ptr, adj, dinv2, N, E); // hop 2
    prop_kernel<<<pgrid, 256, 0, stream>>>(g1, g0, row_ptr, adj, dinv2, N, E); // hop 3
    // hop 4 + final fused (reads g0, writes out directly; g1 scratch only)
    prop_final_kernel<<<(N + 31) / 32, 256, 0, stream>>>(g0, x, xpre, W, b, out,
                                                         row_ptr, adj, dinv, N, E);
    (void)g1;
}